// Round 6
// baseline (1090.404 us; speedup 1.0000x reference)
//
#include <hip/hip_runtime.h>

// ---------------------------------------------------------------------------
// PIDMultiHeadAttention — Round 6.
// Round 5 crashed with a GPU memory fault traced to ONE bug: NS = 512/MT
// gave 8 (not 2) for the MT=64 out-projection, producing OOB LDS reads and
// OOB global writes past d_out. This round = round 5 with NS fixed.
//  * staging via __builtin_amdgcn_global_load_lds width=16 (m97 move)
//  * g-scale deferred to K-segment boundaries (A-tile is pure unscaled loads)
//  * DMA lane map (row = l&15, chunk = l>>4) lands data in MFMA fragment
//    layout; wave LDS ops are 1KiB-contiguous (conflict-free)
// ---------------------------------------------------------------------------

#define D_MODEL 1024
#define T_SEQ   2048
#define B_SZ    2
#define M_ROWS  (B_SZ * T_SEQ)   // 4096
#define N_HEADS 16
#define D_HEAD  64

typedef unsigned short u16;
typedef unsigned int   u32;

typedef short  short8  __attribute__((ext_vector_type(8)));
typedef float  float4v __attribute__((ext_vector_type(4)));

__device__ __forceinline__ float bf2f(u16 u) {
    union { u32 i; float f; } c; c.i = ((u32)u) << 16; return c.f;
}
__device__ __forceinline__ u16 f2bf(float f) {
    union { float f; u32 i; } c; c.f = f;
    u32 i = c.i;
    i += 0x7FFFu + ((i >> 16) & 1u);   // RNE
    return (u16)(i >> 16);
}
__device__ __forceinline__ float ldin(const void* p, int i, int fl) {
    return fl ? ((const float*)p)[i] : bf2f(((const u16*)p)[i]);
}

// async global->LDS, 16B per lane, dst = wave-uniform base + lane*16
__device__ __forceinline__ void gl_lds16(const u16* g, u16* s) {
    __builtin_amdgcn_global_load_lds(
        (const __attribute__((address_space(1))) u32*)g,
        (__attribute__((address_space(3))) u32*)s,
        16, 0, 0);
}

// ---------------------------------------------------------------------------
// 0) wire-dtype detection (unchanged — passing since round 2)
// ---------------------------------------------------------------------------
__global__ void detect_kernel(const u32* __restrict__ x, int* __restrict__ flag)
{
    if (threadIdx.x == 0 && blockIdx.x == 0) {
        int good = 0;
        for (int i = 0; i < 256; ++i) {
            union { u32 u; float f; } c; c.u = x[i];
            float a = fabsf(c.f);
            if (c.f == c.f && a > 1e-8f && a < 1e4f) ++good;
        }
        *flag = (good >= 192) ? 1 : 0;
    }
}

// ---------------------------------------------------------------------------
// 1) cumulative-mean scan (unchanged)
// ---------------------------------------------------------------------------
__global__ __launch_bounds__(256) void scan_partial(
    const void* __restrict__ x, float* __restrict__ csum,
    const int* __restrict__ flagp)
{
    int fl = *flagp;
    int tid = blockIdx.x * 256 + threadIdx.x;   // 32768 = B * 16 * D
    int b = tid >> 14;
    int c = (tid >> 10) & 15;
    int d = tid & 1023;
    int base = (b * T_SEQ + c * 128) * D_MODEL + d;
    float s = 0.f;
#pragma unroll 8
    for (int t = 0; t < 128; ++t) s += ldin(x, base + t * D_MODEL, fl);
    csum[tid] = s;
}

__global__ __launch_bounds__(256) void scan_final(
    const void* __restrict__ x, const float* __restrict__ csum,
    u16* __restrict__ integ, const int* __restrict__ flagp)
{
    int fl = *flagp;
    int tid = blockIdx.x * 256 + threadIdx.x;
    int b = tid >> 14;
    int c = (tid >> 10) & 15;
    int d = tid & 1023;
    float pre = 0.f;
    int cbase = (b << 14) | d;
    for (int cc = 0; cc < c; ++cc) pre += csum[cbase + (cc << 10)];
    int base = (b * T_SEQ + c * 128) * D_MODEL + d;
    float run = pre;
    int t0 = c * 128;
    for (int t = 0; t < 128; ++t) {
        run += ldin(x, base + t * D_MODEL, fl);
        integ[base + t * D_MODEL] = f2bf(run / (float)(t0 + t + 1));
    }
}

// ---------------------------------------------------------------------------
// 2) gate softmax (unchanged)
// ---------------------------------------------------------------------------
__global__ __launch_bounds__(64) void gates_kernel(
    const void* __restrict__ x,
    const void* __restrict__ qWg, const void* __restrict__ qbg,
    const void* __restrict__ kWg, const void* __restrict__ kbg,
    const void* __restrict__ vWg, const void* __restrict__ vbg,
    float* __restrict__ gq, float* __restrict__ gk, float* __restrict__ gv,
    const int* __restrict__ flagp)
{
    int fl = *flagp;
    int row = blockIdx.x;
    int l = threadIdx.x;
    int xb = row * D_MODEL;
    float p[9];
#pragma unroll
    for (int j = 0; j < 9; ++j) p[j] = 0.f;
#pragma unroll 4
    for (int i = 0; i < 16; ++i) {
        int d = l + 64 * i;
        float xv = ldin(x, xb + d, fl);
        p[0] += xv * ldin(qWg, d, fl);
        p[1] += xv * ldin(qWg, 1024 + d, fl);
        p[2] += xv * ldin(qWg, 2048 + d, fl);
        p[3] += xv * ldin(kWg, d, fl);
        p[4] += xv * ldin(kWg, 1024 + d, fl);
        p[5] += xv * ldin(kWg, 2048 + d, fl);
        p[6] += xv * ldin(vWg, d, fl);
        p[7] += xv * ldin(vWg, 1024 + d, fl);
        p[8] += xv * ldin(vWg, 2048 + d, fl);
    }
#pragma unroll
    for (int off = 32; off > 0; off >>= 1) {
#pragma unroll
        for (int j = 0; j < 9; ++j) p[j] += __shfl_down(p[j], off);
    }
    if (l == 0) {
        const void* bgs[3] = { qbg, kbg, vbg };
        float* outs[3] = { gq, gk, gv };
#pragma unroll
        for (int pr = 0; pr < 3; ++pr) {
            float a0 = p[pr * 3 + 0] + ldin(bgs[pr], 0, fl);
            float a1 = p[pr * 3 + 1] + ldin(bgs[pr], 1, fl);
            float a2 = p[pr * 3 + 2] + ldin(bgs[pr], 2, fl);
            float mx = fmaxf(a0, fmaxf(a1, a2));
            float e0 = __expf(a0 - mx), e1 = __expf(a1 - mx), e2 = __expf(a2 - mx);
            float inv = 1.f / (e0 + e1 + e2);
            outs[pr][row * 3 + 0] = e0 * inv;
            outs[pr][row * 3 + 1] = e1 * inv;
            outs[pr][row * 3 + 2] = e2 * inv;
        }
    }
}

// ---------------------------------------------------------------------------
// 3) MFMA GEMM with async LDS staging.
//    Tile: MT x 128 x 32, double-buffered. MODE 0: PID proj (K=3072 seg-major,
//    unscaled bases; g folded at seg boundaries). MODE 1: out proj (K=1024).
//    LDS layout: 16-row "groups" of 1KiB; within a group lane-slot l holds
//    (row = l&15, k-chunk = l>>4) as 16B — matches both the DMA contract
//    (base + lane*16) and the MFMA fragment read pattern.
// ---------------------------------------------------------------------------
struct GemmArgs {
    const void* W[3][3];
    const float* G[3];
    u16* C[3];
};

template<int MODE, int MT>
__global__ __launch_bounds__(256, 2) void mfma_gemm(
    const void* __restrict__ X, const u16* __restrict__ Ib,
    const u16* __restrict__ Abf, GemmArgs args,
    const void* __restrict__ bias, void* __restrict__ outp,
    const int* __restrict__ flagp, int Ktot)
{
    constexpr int NAG  = MT / 16;        // A groups per buffer
    constexpr int NGR  = NAG + 8;        // total groups (B always 8)
    constexpr int NGPW = NGR / 4;        // groups staged per wave
    constexpr int ASZ  = MT * 32;        // A u16 per buffer
    constexpr int NS   = (MT == 128) ? 4 : 2;   // wave N-subtiles (FIXED: was 512/MT -> 8 for MT=64, OOB)

    int fl = *flagp;
    __shared__ __align__(16) u16 As[2 * ASZ];
    __shared__ __align__(16) u16 Bs[2 * 4096];

    int tid = threadIdx.x;
    int l = tid & 63, w = tid >> 6;
    int wm = (MT == 128) ? (w >> 1) : 0;
    int wn = (MT == 128) ? (w & 1) : w;
    int m0 = blockIdx.y * MT, n0 = blockIdx.x * 128;
    int z = blockIdx.z;
    int lane15 = l & 15, quad = l >> 4;
    int l15 = l & 15, kc = (l >> 4) * 8;   // staging lane map

    const void* W0; const void* W1; const void* W2;
    const float* G = nullptr;
    u16* Chead = nullptr;
    if (MODE == 0) {
        W0 = args.W[z][0]; W1 = args.W[z][1]; W2 = args.W[z][2];
        G = args.G[z]; Chead = args.C[z];
    } else {
        W0 = args.W[0][0]; W1 = W0; W2 = W0;
    }

    // VGPR staging fallback: 8 wire elems -> bf16 -> 16B at this lane's slot
    auto stage_v8 = [&](const void* src, int idx, u16* dstg) {
        short8 pk;
        if (fl) {
            float4 t0 = *(const float4*)((const float*)src + idx);
            float4 t1 = *(const float4*)((const float*)src + idx + 4);
            pk[0] = (short)f2bf(t0.x); pk[1] = (short)f2bf(t0.y);
            pk[2] = (short)f2bf(t0.z); pk[3] = (short)f2bf(t0.w);
            pk[4] = (short)f2bf(t1.x); pk[5] = (short)f2bf(t1.y);
            pk[6] = (short)f2bf(t1.z); pk[7] = (short)f2bf(t1.w);
        } else {
            ushort4 a = *(const ushort4*)((const u16*)src + idx);
            ushort4 b = *(const ushort4*)((const u16*)src + idx + 4);
            pk[0] = (short)a.x; pk[1] = (short)a.y; pk[2] = (short)a.z; pk[3] = (short)a.w;
            pk[4] = (short)b.x; pk[5] = (short)b.y; pk[6] = (short)b.z; pk[7] = (short)b.w;
        }
        *(short8*)(dstg + l * 8) = pk;
    };

    auto stage = [&](int k0, int buf) {
        int seg = (MODE == 0) ? (k0 >> 10) : 0;
        int ksrc = k0 & 1023;
        u16* Ad = As + buf * ASZ;
        u16* Bd = Bs + buf * 4096;
#pragma unroll
        for (int i = 0; i < NGPW; ++i) {
            int gid = w * NGPW + i;
            if (gid < NAG) {
                int g = gid;
                int gm = m0 + g * 16 + l15;
                int idx = gm * 1024 + ksrc + kc;
                u16* dst = Ad + g * 512;
                if (MODE == 1) {
                    gl_lds16(Abf + idx, dst);
                } else if (seg == 1) {
                    gl_lds16(Ib + idx, dst);
                } else if (seg == 0) {
                    if (fl) stage_v8(X, idx, dst);
                    else    gl_lds16((const u16*)X + idx, dst);
                } else {
                    // derivative: x[t] - x[t-1], zero at t==0
                    short8 pk;
                    if ((gm & (T_SEQ - 1)) == 0) {
#pragma unroll
                        for (int j = 0; j < 8; ++j) pk[j] = 0;
                    } else if (fl) {
                        const float* xp = (const float*)X;
                        float4 c0 = *(const float4*)(xp + idx);
                        float4 c1 = *(const float4*)(xp + idx + 4);
                        float4 p0 = *(const float4*)(xp + idx - 1024);
                        float4 p1 = *(const float4*)(xp + idx - 1020);
                        pk[0] = (short)f2bf(c0.x - p0.x); pk[1] = (short)f2bf(c0.y - p0.y);
                        pk[2] = (short)f2bf(c0.z - p0.z); pk[3] = (short)f2bf(c0.w - p0.w);
                        pk[4] = (short)f2bf(c1.x - p1.x); pk[5] = (short)f2bf(c1.y - p1.y);
                        pk[6] = (short)f2bf(c1.z - p1.z); pk[7] = (short)f2bf(c1.w - p1.w);
                    } else {
                        const u16* xp = (const u16*)X;
                        ushort4 c0 = *(const ushort4*)(xp + idx);
                        ushort4 c1 = *(const ushort4*)(xp + idx + 4);
                        ushort4 p0 = *(const ushort4*)(xp + idx - 1024);
                        ushort4 p1 = *(const ushort4*)(xp + idx - 1020);
                        pk[0] = (short)f2bf(bf2f(c0.x) - bf2f(p0.x));
                        pk[1] = (short)f2bf(bf2f(c0.y) - bf2f(p0.y));
                        pk[2] = (short)f2bf(bf2f(c0.z) - bf2f(p0.z));
                        pk[3] = (short)f2bf(bf2f(c0.w) - bf2f(p0.w));
                        pk[4] = (short)f2bf(bf2f(c1.x) - bf2f(p1.x));
                        pk[5] = (short)f2bf(bf2f(c1.y) - bf2f(p1.y));
                        pk[6] = (short)f2bf(bf2f(c1.z) - bf2f(p1.z));
                        pk[7] = (short)f2bf(bf2f(c1.w) - bf2f(p1.w));
                    }
                    *(short8*)(dst + l * 8) = pk;
                }
            } else {
                int g = gid - NAG;
                int gn = n0 + g * 16 + l15;
                int idx = gn * 1024 + ksrc + kc;
                const void* Wse = (MODE == 0)
                    ? (seg == 0 ? W0 : (seg == 1 ? W1 : W2)) : W0;
                u16* dst = Bd + g * 512;
                if (fl) stage_v8(Wse, idx, dst);
                else    gl_lds16((const u16*)Wse + idx, dst);
            }
        }
    };

    float4v accs[4][NS], acct[4][NS];
#pragma unroll
    for (int i = 0; i < 4; ++i)
#pragma unroll
        for (int j = 0; j < NS; ++j)
#pragma unroll
            for (int r = 0; r < 4; ++r) { accs[i][j][r] = 0.f; acct[i][j][r] = 0.f; }

    int nIt = Ktot >> 5;
    stage(0, 0);

    for (int it = 0; it < nIt; ++it) {
        __syncthreads();                 // drains vmcnt -> buf[cur] ready
        int cur = it & 1;
        if (it + 1 < nIt) stage((it + 1) << 5, 1 - cur);

        short8 af[4], bfr[NS];
#pragma unroll
        for (int ms = 0; ms < 4; ++ms)
            af[ms] = *(const short8*)&As[cur * ASZ + (wm * 4 + ms) * 512 + quad * 128 + lane15 * 8];
#pragma unroll
        for (int ns = 0; ns < NS; ++ns)
            bfr[ns] = *(const short8*)&Bs[cur * 4096 + (wn * NS + ns) * 512 + quad * 128 + lane15 * 8];
#pragma unroll
        for (int ms = 0; ms < 4; ++ms)
#pragma unroll
            for (int ns = 0; ns < NS; ++ns)
                accs[ms][ns] = __builtin_amdgcn_mfma_f32_16x16x32_bf16(
                    af[ms], bfr[ns], accs[ms][ns], 0, 0, 0);

        // fold seg-partial into total with per-row g at segment boundaries
        if (MODE == 0 && (it & 31) == 31) {
            int seg = it >> 5;
#pragma unroll
            for (int ms = 0; ms < 4; ++ms) {
#pragma unroll
                for (int r = 0; r < 4; ++r) {
                    int m = m0 + wm * 64 + ms * 16 + quad * 4 + r;
                    float gv = G[m * 3 + seg];
#pragma unroll
                    for (int ns = 0; ns < NS; ++ns) {
                        acct[ms][ns][r] += gv * accs[ms][ns][r];
                        accs[ms][ns][r] = 0.f;
                    }
                }
            }
        }
    }

    // ---- epilogue ----
#pragma unroll
    for (int ms = 0; ms < 4; ++ms) {
#pragma unroll
        for (int r = 0; r < 4; ++r) {
            int m = m0 + wm * 64 + ms * 16 + quad * 4 + r;
#pragma unroll
            for (int ns = 0; ns < NS; ++ns) {
                int n = n0 + (wn * NS + ns) * 16 + lane15;
                if (MODE == 0) {
                    float vv = acct[ms][ns][r];
                    int b = m >> 11, t = m & (T_SEQ - 1);
                    int h = n >> 6,  d = n & 63;
                    Chead[(((b << 4) + h) * T_SEQ + t) * 64 + d] = f2bf(vv);
                } else {
                    float vv = accs[ms][ns][r] + ldin(bias, n, fl);
                    if (fl) ((float*)outp)[m * 1024 + n] = vv;
                    else    ((u16*)outp)[m * 1024 + n] = f2bf(vv);
                }
            }
        }
    }
}

// ---------------------------------------------------------------------------
// 4) MFMA flash attention (unchanged from round 3/4 — passing)
// ---------------------------------------------------------------------------
__global__ __launch_bounds__(256) void attn_mfma(
    const u16* __restrict__ Qh, const u16* __restrict__ Kh,
    const u16* __restrict__ Vh, u16* __restrict__ AO)
{
    int bx = blockIdx.x;          // 1024 = B*H*(T/64)
    int qt = bx & 31;
    int bh = bx >> 5;             // 0..31
    int h  = bh & 15;
    int b  = bh >> 4;
    int tid = threadIdx.x;
    int l   = tid & 63;
    int w   = tid >> 6;
    int lane15 = l & 15;
    int quad   = l >> 4;

    __shared__ __align__(16) u16 Ks[64 * 72];
    __shared__ __align__(16) u16 Vt[64 * 72];   // transposed: [d][t_local]
    __shared__ __align__(16) u16 Ps[4 * 16 * 72];

    const u16* Qb = Qh + bh * (T_SEQ * 64);
    const u16* Kb = Kh + bh * (T_SEQ * 64);
    const u16* Vb = Vh + bh * (T_SEQ * 64);

    int qrow = qt * 64 + w * 16 + lane15;
    short8 qf[2];
#pragma unroll
    for (int ks = 0; ks < 2; ++ks)
        qf[ks] = *(const short8*)&Qb[qrow * 64 + ks * 32 + quad * 8];

    float4v oacc[4];
#pragma unroll
    for (int ds = 0; ds < 4; ++ds)
#pragma unroll
        for (int r = 0; r < 4; ++r) oacc[ds][r] = 0.f;
    float mrun[4], lrun[4];
#pragma unroll
    for (int r = 0; r < 4; ++r) { mrun[r] = -1e30f; lrun[r] = 0.f; }

    int srow = tid >> 2;
    int sdc  = (tid & 3) * 16;

    for (int kt = 0; kt <= qt; ++kt) {
        {
            const u16* kp = &Kb[(kt * 64 + srow) * 64 + sdc];
            ushort4 a = *(const ushort4*)kp;
            ushort4 c = *(const ushort4*)(kp + 4);
            ushort4 d2 = *(const ushort4*)(kp + 8);
            ushort4 e = *(const ushort4*)(kp + 12);
            short8 p0, p1;
            p0[0]=a.x; p0[1]=a.y; p0[2]=a.z; p0[3]=a.w;
            p0[4]=c.x; p0[5]=c.y; p0[6]=c.z; p0[7]=c.w;
            p1[0]=d2.x; p1[1]=d2.y; p1[2]=d2.z; p1[3]=d2.w;
            p1[4]=e.x; p1[5]=e.y; p1[6]=e.z; p1[7]=e.w;
            *(short8*)&Ks[srow * 72 + sdc] = p0;
            *(short8*)&Ks[srow * 72 + sdc + 8] = p1;

            const u16* vp = &Vb[(kt * 64 + srow) * 64 + sdc];
            u16 vv[16];
            *(ushort4*)&vv[0]  = *(const ushort4*)vp;
            *(ushort4*)&vv[4]  = *(const ushort4*)(vp + 4);
            *(ushort4*)&vv[8]  = *(const ushort4*)(vp + 8);
            *(ushort4*)&vv[12] = *(const ushort4*)(vp + 12);
#pragma unroll
            for (int e2 = 0; e2 < 16; ++e2)
                Vt[(sdc + e2) * 72 + srow] = vv[e2];
        }
        __syncthreads();

        float4v sacc[4];
#pragma unroll
        for (int ns = 0; ns < 4; ++ns)
#pragma unroll
            for (int r = 0; r < 4; ++r) sacc[ns][r] = 0.f;
#pragma unroll
        for (int ks = 0; ks < 2; ++ks) {
#pragma unroll
            for (int ns = 0; ns < 4; ++ns) {
                short8 bfk = *(const short8*)&Ks[(ns * 16 + lane15) * 72 + ks * 32 + quad * 8];
                sacc[ns] = __builtin_amdgcn_mfma_f32_16x16x32_bf16(
                    qf[ks], bfk, sacc[ns], 0, 0, 0);
            }
        }

        int qg0 = qt * 64 + w * 16 + quad * 4;
#pragma unroll
        for (int ns = 0; ns < 4; ++ns) {
            int kg = kt * 64 + ns * 16 + lane15;
#pragma unroll
            for (int r = 0; r < 4; ++r) {
                float s = sacc[ns][r] * 0.125f;
                sacc[ns][r] = (kg > qg0 + r) ? -1e30f : s;
            }
        }
#pragma unroll
        for (int r = 0; r < 4; ++r) {
            float mx = fmaxf(fmaxf(sacc[0][r], sacc[1][r]),
                             fmaxf(sacc[2][r], sacc[3][r]));
#pragma unroll
            for (int m2 = 1; m2 < 16; m2 <<= 1)
                mx = fmaxf(mx, __shfl_xor(mx, m2, 64));
            float mnew = fmaxf(mrun[r], mx);
            float al = __expf(mrun[r] - mnew);
            float rs = 0.f;
#pragma unroll
            for (int ns = 0; ns < 4; ++ns) {
                float p = __expf(sacc[ns][r] - mnew);
                sacc[ns][r] = p;
                rs += p;
            }
#pragma unroll
            for (int m2 = 1; m2 < 16; m2 <<= 1)
                rs += __shfl_xor(rs, m2, 64);
            lrun[r] = lrun[r] * al + rs;
            mrun[r] = mnew;
#pragma unroll
            for (int ds = 0; ds < 4; ++ds) oacc[ds][r] *= al;
        }

        u16* Pw = &Ps[w * 16 * 72];
#pragma unroll
        for (int ns = 0; ns < 4; ++ns)
#pragma unroll
            for (int r = 0; r < 4; ++r)
                Pw[(quad * 4 + r) * 72 + ns * 16 + lane15] = f2bf(sacc[ns][r]);

#pragma unroll
        for (int ks = 0; ks < 2; ++ks) {
            short8 afp = *(const short8*)&Pw[lane15 * 72 + ks * 32 + quad * 8];
#pragma unroll
            for (int ds = 0; ds < 4; ++ds) {
                short8 bfv = *(const short8*)&Vt[(ds * 16 + lane15) * 72 + ks * 32 + quad * 8];
                oacc[ds] = __builtin_amdgcn_mfma_f32_16x16x32_bf16(
                    afp, bfv, oacc[ds], 0, 0, 0);
            }
        }
        __syncthreads();
    }

#pragma unroll
    for (int r = 0; r < 4; ++r) {
        float inv = 1.f / lrun[r];
        int t = qt * 64 + w * 16 + quad * 4 + r;
        int orow = (b * T_SEQ + t) * 1024 + h * 64;
#pragma unroll
        for (int ds = 0; ds < 4; ++ds)
            AO[orow + ds * 16 + lane15] = f2bf(oacc[ds][r] * inv);
    }
}

// ---------------------------------------------------------------------------
extern "C" void kernel_launch(void* const* d_in, const int* in_sizes, int n_in,
                              void* d_out, int out_size, void* d_ws, size_t ws_size,
                              hipStream_t stream)
{
    const void* x   = d_in[0];
    const void* qWp = d_in[1];
    const void* qWi = d_in[2];
    const void* qWd = d_in[3];
    const void* qWg = d_in[4];
    const void* qbg = d_in[5];
    const void* kWp = d_in[6];
    const void* kWi = d_in[7];
    const void* kWd = d_in[8];
    const void* kWg = d_in[9];
    const void* kbg = d_in[10];
    const void* vWp = d_in[11];
    const void* vWi = d_in[12];
    const void* vWd = d_in[13];
    const void* vWg = d_in[14];
    const void* vbg = d_in[15];
    const void* oW  = d_in[16];
    const void* ob  = d_in[17];

    // ws layout (33 MiB total — unchanged, proven):
    int*   flag = (int*)d_ws;
    float* fws  = (float*)d_ws;
    float* csum = fws + 64;
    float* gq   = csum + 32768;
    float* gk   = gq + 3 * M_ROWS;
    float* gv   = gk + 3 * M_ROWS;
    const size_t SZ = (size_t)M_ROWS * D_MODEL;
    u16* Ib = (u16*)((char*)d_ws + (1u << 20));
    u16* AO = Ib;                  // alias, disjoint in time
    u16* Qh = Ib + SZ;
    u16* Kh = Qh + SZ;
    u16* Vh = Kh + SZ;

    detect_kernel<<<1, 64, 0, stream>>>((const u32*)x, flag);
    scan_partial<<<128, 256, 0, stream>>>(x, csum, flag);
    scan_final<<<128, 256, 0, stream>>>(x, csum, Ib, flag);
    gates_kernel<<<M_ROWS, 64, 0, stream>>>(x, qWg, qbg, kWg, kbg, vWg, vbg,
                                            gq, gk, gv, flag);

    GemmArgs pa;
    pa.W[0][0] = qWp; pa.W[0][1] = qWi; pa.W[0][2] = qWd;
    pa.W[1][0] = kWp; pa.W[1][1] = kWi; pa.W[1][2] = kWd;
    pa.W[2][0] = vWp; pa.W[2][1] = vWi; pa.W[2][2] = vWd;
    pa.G[0] = gq; pa.G[1] = gk; pa.G[2] = gv;
    pa.C[0] = Qh; pa.C[1] = Kh; pa.C[2] = Vh;
    mfma_gemm<0, 128><<<dim3(8, 32, 3), 256, 0, stream>>>(
        x, Ib, nullptr, pa, nullptr, nullptr, flag, 3072);

    attn_mfma<<<B_SZ * N_HEADS * (T_SEQ / 64), 256, 0, stream>>>(Qh, Kh, Vh, AO);

    GemmArgs oa = {};
    oa.W[0][0] = oW;
    mfma_gemm<1, 64><<<dim3(8, 64, 1), 256, 0, stream>>>(
        nullptr, nullptr, AO, oa, ob, d_out, flag, 1024);
}

// Round 7
// 743.992 us; speedup vs baseline: 1.4656x; 1.4656x over previous
//
#include <hip/hip_runtime.h>

// ---------------------------------------------------------------------------
// PIDMultiHeadAttention — Round 7.
// Round 6's DMA staging serialized (compiler drains vmcnt(0) before the
// ds_reads it can't disambiguate from the async LDS writes): 723 us, both
// pipes idle. This round keeps round 6's two proven wins and restores the
// round-4 staging engine that measured 293 us:
//  * register-prefetch vector loads + ds_write_b128 (round-4 engine)
//  * fragment-major LDS layout (round 6: SQ_LDS_BANK_CONFLICT = 0)
//  * deferred g-scale at K-segment boundaries (round 6: correct) -> staging
//    for seg0/seg1/out-proj is a pure uint4 copy, no element VALU
// ---------------------------------------------------------------------------

#define D_MODEL 1024
#define T_SEQ   2048
#define B_SZ    2
#define M_ROWS  (B_SZ * T_SEQ)   // 4096
#define N_HEADS 16
#define D_HEAD  64

typedef unsigned short u16;
typedef unsigned int   u32;

typedef short  short8  __attribute__((ext_vector_type(8)));
typedef float  float4v __attribute__((ext_vector_type(4)));

__device__ __forceinline__ float bf2f(u16 u) {
    union { u32 i; float f; } c; c.i = ((u32)u) << 16; return c.f;
}
__device__ __forceinline__ u16 f2bf(float f) {
    union { float f; u32 i; } c; c.f = f;
    u32 i = c.i;
    i += 0x7FFFu + ((i >> 16) & 1u);   // RNE
    return (u16)(i >> 16);
}
__device__ __forceinline__ float ldin(const void* p, int i, int fl) {
    return fl ? ((const float*)p)[i] : bf2f(((const u16*)p)[i]);
}

// ---------------------------------------------------------------------------
// 0) wire-dtype detection (unchanged — passing since round 2)
// ---------------------------------------------------------------------------
__global__ void detect_kernel(const u32* __restrict__ x, int* __restrict__ flag)
{
    if (threadIdx.x == 0 && blockIdx.x == 0) {
        int good = 0;
        for (int i = 0; i < 256; ++i) {
            union { u32 u; float f; } c; c.u = x[i];
            float a = fabsf(c.f);
            if (c.f == c.f && a > 1e-8f && a < 1e4f) ++good;
        }
        *flag = (good >= 192) ? 1 : 0;
    }
}

// ---------------------------------------------------------------------------
// 1) cumulative-mean scan (unchanged — coalesced across lanes, cheap)
// ---------------------------------------------------------------------------
__global__ __launch_bounds__(256) void scan_partial(
    const void* __restrict__ x, float* __restrict__ csum,
    const int* __restrict__ flagp)
{
    int fl = *flagp;
    int tid = blockIdx.x * 256 + threadIdx.x;   // 32768 = B * 16 * D
    int b = tid >> 14;
    int c = (tid >> 10) & 15;
    int d = tid & 1023;
    int base = (b * T_SEQ + c * 128) * D_MODEL + d;
    float s = 0.f;
#pragma unroll 8
    for (int t = 0; t < 128; ++t) s += ldin(x, base + t * D_MODEL, fl);
    csum[tid] = s;
}

__global__ __launch_bounds__(256) void scan_final(
    const void* __restrict__ x, const float* __restrict__ csum,
    u16* __restrict__ integ, const int* __restrict__ flagp)
{
    int fl = *flagp;
    int tid = blockIdx.x * 256 + threadIdx.x;
    int b = tid >> 14;
    int c = (tid >> 10) & 15;
    int d = tid & 1023;
    float pre = 0.f;
    int cbase = (b << 14) | d;
    for (int cc = 0; cc < c; ++cc) pre += csum[cbase + (cc << 10)];
    int base = (b * T_SEQ + c * 128) * D_MODEL + d;
    float run = pre;
    int t0 = c * 128;
    for (int t = 0; t < 128; ++t) {
        run += ldin(x, base + t * D_MODEL, fl);
        integ[base + t * D_MODEL] = f2bf(run / (float)(t0 + t + 1));
    }
}

// ---------------------------------------------------------------------------
// 2) gate softmax (unchanged)
// ---------------------------------------------------------------------------
__global__ __launch_bounds__(64) void gates_kernel(
    const void* __restrict__ x,
    const void* __restrict__ qWg, const void* __restrict__ qbg,
    const void* __restrict__ kWg, const void* __restrict__ kbg,
    const void* __restrict__ vWg, const void* __restrict__ vbg,
    float* __restrict__ gq, float* __restrict__ gk, float* __restrict__ gv,
    const int* __restrict__ flagp)
{
    int fl = *flagp;
    int row = blockIdx.x;
    int l = threadIdx.x;
    int xb = row * D_MODEL;
    float p[9];
#pragma unroll
    for (int j = 0; j < 9; ++j) p[j] = 0.f;
#pragma unroll 4
    for (int i = 0; i < 16; ++i) {
        int d = l + 64 * i;
        float xv = ldin(x, xb + d, fl);
        p[0] += xv * ldin(qWg, d, fl);
        p[1] += xv * ldin(qWg, 1024 + d, fl);
        p[2] += xv * ldin(qWg, 2048 + d, fl);
        p[3] += xv * ldin(kWg, d, fl);
        p[4] += xv * ldin(kWg, 1024 + d, fl);
        p[5] += xv * ldin(kWg, 2048 + d, fl);
        p[6] += xv * ldin(vWg, d, fl);
        p[7] += xv * ldin(vWg, 1024 + d, fl);
        p[8] += xv * ldin(vWg, 2048 + d, fl);
    }
#pragma unroll
    for (int off = 32; off > 0; off >>= 1) {
#pragma unroll
        for (int j = 0; j < 9; ++j) p[j] += __shfl_down(p[j], off);
    }
    if (l == 0) {
        const void* bgs[3] = { qbg, kbg, vbg };
        float* outs[3] = { gq, gk, gv };
#pragma unroll
        for (int pr = 0; pr < 3; ++pr) {
            float a0 = p[pr * 3 + 0] + ldin(bgs[pr], 0, fl);
            float a1 = p[pr * 3 + 1] + ldin(bgs[pr], 1, fl);
            float a2 = p[pr * 3 + 2] + ldin(bgs[pr], 2, fl);
            float mx = fmaxf(a0, fmaxf(a1, a2));
            float e0 = __expf(a0 - mx), e1 = __expf(a1 - mx), e2 = __expf(a2 - mx);
            float inv = 1.f / (e0 + e1 + e2);
            outs[pr][row * 3 + 0] = e0 * inv;
            outs[pr][row * 3 + 1] = e1 * inv;
            outs[pr][row * 3 + 2] = e2 * inv;
        }
    }
}

// ---------------------------------------------------------------------------
// 3) MFMA GEMM, MT x 128 x 32 tiles, double-buffered register-prefetch
//    staging (round-4 engine) into fragment-major LDS (round-6 layout).
//    MODE 0: PID proj (K=3072 seg-major; g folded at seg boundaries).
//    MODE 1: out proj (K=1024, +bias, wire-dtype store).
//    LDS offset (u16) for (row r, k-chunk cs): group (r>>4) of 1KiB;
//    inside: slot (cs*16 + (r&15)) * 16B  — both ds_write_b128 and
//    ds_read_b128 are 1KiB-contiguous per wave (0 conflicts, round 6).
// ---------------------------------------------------------------------------
struct GemmArgs {
    const void* W[3][3];
    const float* G[3];
    u16* C[3];
};

template<int MODE, int MT>
__global__ __launch_bounds__(256, 2) void mfma_gemm(
    const void* __restrict__ X, const u16* __restrict__ Ib,
    const u16* __restrict__ Abf, GemmArgs args,
    const void* __restrict__ bias, void* __restrict__ outp,
    const int* __restrict__ flagp, int Ktot)
{
    constexpr int NAC = MT / 64;               // A 64-row chunks (1 or 2)
    constexpr int ASZ = MT * 32;               // A u16 per buffer
    constexpr int NS  = (MT == 128) ? 4 : 2;   // wave N-subtiles

    int fl = *flagp;
    __shared__ __align__(16) u16 As[2 * ASZ];
    __shared__ __align__(16) u16 Bs[2 * 4096];

    int tid = threadIdx.x;
    int l = tid & 63, w = tid >> 6;
    int wm = (MT == 128) ? (w >> 1) : 0;
    int wn = (MT == 128) ? (w & 1) : w;
    int m0 = blockIdx.y * MT, n0 = blockIdx.x * 128;
    int z = blockIdx.z;
    int lane15 = l & 15, quad = l >> 4;
    int srow = tid >> 2;       // staging row 0..63 within 64-row chunk
    int cs = tid & 3;          // k-chunk 0..3
    int skof = cs * 8;

    // LDS u16 offset for (row, chunk)
    auto aoff = [](int r, int c) {
        return ((r >> 4) << 9) + (((c << 4) | (r & 15)) << 3);
    };

    const void* W0; const void* W1; const void* W2;
    const float* G = nullptr;
    u16* Chead = nullptr;
    if (MODE == 0) {
        W0 = args.W[z][0]; W1 = args.W[z][1]; W2 = args.W[z][2];
        G = args.G[z]; Chead = args.C[z];
    } else {
        W0 = args.W[0][0]; W1 = W0; W2 = W0;
    }

    bool t0r[NAC];
#pragma unroll
    for (int c = 0; c < NAC; ++c)
        t0r[c] = (((m0 + c * 64 + srow) & (T_SEQ - 1)) == 0);

    uint4 rA[NAC], rP[NAC], rB[2];

    // prefetch next tile's bytes into registers (bf16 wire only)
    auto load_phase = [&](int k0) {
        int seg = (MODE == 0) ? (k0 >> 10) : 0;
        int ksrc = k0 & 1023;
        const u16* Asrc = (MODE == 1) ? Abf : (seg == 1 ? Ib : (const u16*)X);
#pragma unroll
        for (int c = 0; c < NAC; ++c) {
            int gm = m0 + c * 64 + srow;
            int idx = gm * 1024 + ksrc + skof;
            rA[c] = *(const uint4*)(Asrc + idx);
            if (MODE == 0 && seg == 2)
                rP[c] = t0r[c] ? rA[c] : *(const uint4*)(Asrc + idx - 1024);
        }
        const u16* Wse = (const u16*)((MODE == 0)
            ? (seg == 0 ? W0 : (seg == 1 ? W1 : W2)) : W0);
#pragma unroll
        for (int c = 0; c < 2; ++c) {
            int gn = n0 + c * 64 + srow;
            rB[c] = *(const uint4*)(Wse + gn * 1024 + ksrc + skof);
        }
    };

    // diff-pack: bf16 pairs packed in u32 words, out = cur - prev (bf16 RNE)
    auto diffw = [](u32 cw, u32 pw) -> u32 {
        float lo = bf2f((u16)(cw & 0xffff)) - bf2f((u16)(pw & 0xffff));
        float hi = bf2f((u16)(cw >> 16))   - bf2f((u16)(pw >> 16));
        return (u32)f2bf(lo) | ((u32)f2bf(hi) << 16);
    };

    auto store_phase = [&](int k0, int buf) {
        int seg = (MODE == 0) ? (k0 >> 10) : 0;
        int ksrc = k0 & 1023;
        u16* Ad = As + buf * ASZ;
        u16* Bd = Bs + buf * 4096;
        if (!fl) {
#pragma unroll
            for (int c = 0; c < NAC; ++c) {
                int r = c * 64 + srow;
                if (MODE == 0 && seg == 2) {
                    uint4 o;
                    o.x = diffw(rA[c].x, rP[c].x);
                    o.y = diffw(rA[c].y, rP[c].y);
                    o.z = diffw(rA[c].z, rP[c].z);
                    o.w = diffw(rA[c].w, rP[c].w);
                    *(uint4*)&Ad[aoff(r, cs)] = o;
                } else {
                    *(uint4*)&Ad[aoff(r, cs)] = rA[c];   // pure copy
                }
            }
#pragma unroll
            for (int c = 0; c < 2; ++c)
                *(uint4*)&Bd[aoff(c * 64 + srow, cs)] = rB[c];
        } else {
            // fp32-wire insurance path: direct load + convert (slow is fine)
#pragma unroll
            for (int c = 0; c < NAC; ++c) {
                int gm = m0 + c * 64 + srow;
                int idx = gm * 1024 + ksrc + skof;
                int r = c * 64 + srow;
                if (MODE == 1 || seg == 1) {
                    const u16* s = (MODE == 1) ? Abf : Ib;
                    *(uint4*)&Ad[aoff(r, cs)] = *(const uint4*)(s + idx);
                } else {
                    const float* xp = (const float*)X;
                    float v[8];
                    float4 a0 = *(const float4*)(xp + idx);
                    float4 a1 = *(const float4*)(xp + idx + 4);
                    v[0]=a0.x; v[1]=a0.y; v[2]=a0.z; v[3]=a0.w;
                    v[4]=a1.x; v[5]=a1.y; v[6]=a1.z; v[7]=a1.w;
                    if (MODE == 0 && seg == 2) {
                        if (t0r[c]) {
#pragma unroll
                            for (int j = 0; j < 8; ++j) v[j] = 0.f;
                        } else {
                            float4 p0 = *(const float4*)(xp + idx - 1024);
                            float4 p1 = *(const float4*)(xp + idx - 1020);
                            v[0]-=p0.x; v[1]-=p0.y; v[2]-=p0.z; v[3]-=p0.w;
                            v[4]-=p1.x; v[5]-=p1.y; v[6]-=p1.z; v[7]-=p1.w;
                        }
                    }
                    short8 pk;
#pragma unroll
                    for (int j = 0; j < 8; ++j) pk[j] = (short)f2bf(v[j]);
                    *(short8*)&Ad[aoff(r, cs)] = pk;
                }
            }
            const float* Wse = (const float*)((MODE == 0)
                ? (seg == 0 ? W0 : (seg == 1 ? W1 : W2)) : W0);
#pragma unroll
            for (int c = 0; c < 2; ++c) {
                int gn = n0 + c * 64 + srow;
                int idx = gn * 1024 + ksrc + skof;
                float4 b0 = *(const float4*)(Wse + idx);
                float4 b1 = *(const float4*)(Wse + idx + 4);
                short8 pk;
                pk[0]=(short)f2bf(b0.x); pk[1]=(short)f2bf(b0.y);
                pk[2]=(short)f2bf(b0.z); pk[3]=(short)f2bf(b0.w);
                pk[4]=(short)f2bf(b1.x); pk[5]=(short)f2bf(b1.y);
                pk[6]=(short)f2bf(b1.z); pk[7]=(short)f2bf(b1.w);
                *(short8*)&Bd[aoff(c * 64 + srow, cs)] = pk;
            }
        }
    };

    float4v accs[4][NS], acct[4][NS];
#pragma unroll
    for (int i = 0; i < 4; ++i)
#pragma unroll
        for (int j = 0; j < NS; ++j)
#pragma unroll
            for (int r = 0; r < 4; ++r) { accs[i][j][r] = 0.f; acct[i][j][r] = 0.f; }

    int nIt = Ktot >> 5;
    if (!fl) load_phase(0);
    store_phase(0, 0);

    for (int it = 0; it < nIt; ++it) {
        __syncthreads();
        int cur = it & 1;
        if (!fl && it + 1 < nIt) load_phase((it + 1) << 5);

        short8 af[4], bfr[NS];
#pragma unroll
        for (int ms = 0; ms < 4; ++ms)
            af[ms] = *(const short8*)&As[cur * ASZ + (wm * 4 + ms) * 512 + quad * 128 + lane15 * 8];
#pragma unroll
        for (int ns = 0; ns < NS; ++ns)
            bfr[ns] = *(const short8*)&Bs[cur * 4096 + (wn * NS + ns) * 512 + quad * 128 + lane15 * 8];
#pragma unroll
        for (int ms = 0; ms < 4; ++ms)
#pragma unroll
            for (int ns = 0; ns < NS; ++ns)
                accs[ms][ns] = __builtin_amdgcn_mfma_f32_16x16x32_bf16(
                    af[ms], bfr[ns], accs[ms][ns], 0, 0, 0);

        if (it + 1 < nIt) store_phase((it + 1) << 5, 1 - cur);

        // fold seg-partial into total with per-row g at segment boundaries
        if (MODE == 0 && (it & 31) == 31) {
            int seg = it >> 5;
#pragma unroll
            for (int ms = 0; ms < 4; ++ms) {
#pragma unroll
                for (int r = 0; r < 4; ++r) {
                    int m = m0 + wm * 64 + ms * 16 + quad * 4 + r;
                    float gv = G[m * 3 + seg];
#pragma unroll
                    for (int ns = 0; ns < NS; ++ns) {
                        acct[ms][ns][r] += gv * accs[ms][ns][r];
                        accs[ms][ns][r] = 0.f;
                    }
                }
            }
        }
    }

    // ---- epilogue (round-6 proven) ----
#pragma unroll
    for (int ms = 0; ms < 4; ++ms) {
#pragma unroll
        for (int r = 0; r < 4; ++r) {
            int m = m0 + wm * 64 + ms * 16 + quad * 4 + r;
#pragma unroll
            for (int ns = 0; ns < NS; ++ns) {
                int n = n0 + (wn * NS + ns) * 16 + lane15;
                if (MODE == 0) {
                    float vv = acct[ms][ns][r];
                    int b = m >> 11, t = m & (T_SEQ - 1);
                    int h = n >> 6,  d = n & 63;
                    Chead[(((b << 4) + h) * T_SEQ + t) * 64 + d] = f2bf(vv);
                } else {
                    float vv = accs[ms][ns][r] + ldin(bias, n, fl);
                    if (fl) ((float*)outp)[m * 1024 + n] = vv;
                    else    ((u16*)outp)[m * 1024 + n] = f2bf(vv);
                }
            }
        }
    }
}

// ---------------------------------------------------------------------------
// 4) MFMA flash attention (unchanged — passing since round 3)
// ---------------------------------------------------------------------------
__global__ __launch_bounds__(256) void attn_mfma(
    const u16* __restrict__ Qh, const u16* __restrict__ Kh,
    const u16* __restrict__ Vh, u16* __restrict__ AO)
{
    int bx = blockIdx.x;          // 1024 = B*H*(T/64)
    int qt = bx & 31;
    int bh = bx >> 5;             // 0..31
    int h  = bh & 15;
    int b  = bh >> 4;
    int tid = threadIdx.x;
    int l   = tid & 63;
    int w   = tid >> 6;
    int lane15 = l & 15;
    int quad   = l >> 4;

    __shared__ __align__(16) u16 Ks[64 * 72];
    __shared__ __align__(16) u16 Vt[64 * 72];   // transposed: [d][t_local]
    __shared__ __align__(16) u16 Ps[4 * 16 * 72];

    const u16* Qb = Qh + bh * (T_SEQ * 64);
    const u16* Kb = Kh + bh * (T_SEQ * 64);
    const u16* Vb = Vh + bh * (T_SEQ * 64);

    int qrow = qt * 64 + w * 16 + lane15;
    short8 qf[2];
#pragma unroll
    for (int ks = 0; ks < 2; ++ks)
        qf[ks] = *(const short8*)&Qb[qrow * 64 + ks * 32 + quad * 8];

    float4v oacc[4];
#pragma unroll
    for (int ds = 0; ds < 4; ++ds)
#pragma unroll
        for (int r = 0; r < 4; ++r) oacc[ds][r] = 0.f;
    float mrun[4], lrun[4];
#pragma unroll
    for (int r = 0; r < 4; ++r) { mrun[r] = -1e30f; lrun[r] = 0.f; }

    int srow = tid >> 2;
    int sdc  = (tid & 3) * 16;

    for (int kt = 0; kt <= qt; ++kt) {
        {
            const u16* kp = &Kb[(kt * 64 + srow) * 64 + sdc];
            ushort4 a = *(const ushort4*)kp;
            ushort4 c = *(const ushort4*)(kp + 4);
            ushort4 d2 = *(const ushort4*)(kp + 8);
            ushort4 e = *(const ushort4*)(kp + 12);
            short8 p0, p1;
            p0[0]=a.x; p0[1]=a.y; p0[2]=a.z; p0[3]=a.w;
            p0[4]=c.x; p0[5]=c.y; p0[6]=c.z; p0[7]=c.w;
            p1[0]=d2.x; p1[1]=d2.y; p1[2]=d2.z; p1[3]=d2.w;
            p1[4]=e.x; p1[5]=e.y; p1[6]=e.z; p1[7]=e.w;
            *(short8*)&Ks[srow * 72 + sdc] = p0;
            *(short8*)&Ks[srow * 72 + sdc + 8] = p1;

            const u16* vp = &Vb[(kt * 64 + srow) * 64 + sdc];
            u16 vv[16];
            *(ushort4*)&vv[0]  = *(const ushort4*)vp;
            *(ushort4*)&vv[4]  = *(const ushort4*)(vp + 4);
            *(ushort4*)&vv[8]  = *(const ushort4*)(vp + 8);
            *(ushort4*)&vv[12] = *(const ushort4*)(vp + 12);
#pragma unroll
            for (int e2 = 0; e2 < 16; ++e2)
                Vt[(sdc + e2) * 72 + srow] = vv[e2];
        }
        __syncthreads();

        float4v sacc[4];
#pragma unroll
        for (int ns = 0; ns < 4; ++ns)
#pragma unroll
            for (int r = 0; r < 4; ++r) sacc[ns][r] = 0.f;
#pragma unroll
        for (int ks = 0; ks < 2; ++ks) {
#pragma unroll
            for (int ns = 0; ns < 4; ++ns) {
                short8 bfk = *(const short8*)&Ks[(ns * 16 + lane15) * 72 + ks * 32 + quad * 8];
                sacc[ns] = __builtin_amdgcn_mfma_f32_16x16x32_bf16(
                    qf[ks], bfk, sacc[ns], 0, 0, 0);
            }
        }

        int qg0 = qt * 64 + w * 16 + quad * 4;
#pragma unroll
        for (int ns = 0; ns < 4; ++ns) {
            int kg = kt * 64 + ns * 16 + lane15;
#pragma unroll
            for (int r = 0; r < 4; ++r) {
                float s = sacc[ns][r] * 0.125f;
                sacc[ns][r] = (kg > qg0 + r) ? -1e30f : s;
            }
        }
#pragma unroll
        for (int r = 0; r < 4; ++r) {
            float mx = fmaxf(fmaxf(sacc[0][r], sacc[1][r]),
                             fmaxf(sacc[2][r], sacc[3][r]));
#pragma unroll
            for (int m2 = 1; m2 < 16; m2 <<= 1)
                mx = fmaxf(mx, __shfl_xor(mx, m2, 64));
            float mnew = fmaxf(mrun[r], mx);
            float al = __expf(mrun[r] - mnew);
            float rs = 0.f;
#pragma unroll
            for (int ns = 0; ns < 4; ++ns) {
                float p = __expf(sacc[ns][r] - mnew);
                sacc[ns][r] = p;
                rs += p;
            }
#pragma unroll
            for (int m2 = 1; m2 < 16; m2 <<= 1)
                rs += __shfl_xor(rs, m2, 64);
            lrun[r] = lrun[r] * al + rs;
            mrun[r] = mnew;
#pragma unroll
            for (int ds = 0; ds < 4; ++ds) oacc[ds][r] *= al;
        }

        u16* Pw = &Ps[w * 16 * 72];
#pragma unroll
        for (int ns = 0; ns < 4; ++ns)
#pragma unroll
            for (int r = 0; r < 4; ++r)
                Pw[(quad * 4 + r) * 72 + ns * 16 + lane15] = f2bf(sacc[ns][r]);

#pragma unroll
        for (int ks = 0; ks < 2; ++ks) {
            short8 afp = *(const short8*)&Pw[lane15 * 72 + ks * 32 + quad * 8];
#pragma unroll
            for (int ds = 0; ds < 4; ++ds) {
                short8 bfv = *(const short8*)&Vt[(ds * 16 + lane15) * 72 + ks * 32 + quad * 8];
                oacc[ds] = __builtin_amdgcn_mfma_f32_16x16x32_bf16(
                    afp, bfv, oacc[ds], 0, 0, 0);
            }
        }
        __syncthreads();
    }

#pragma unroll
    for (int r = 0; r < 4; ++r) {
        float inv = 1.f / lrun[r];
        int t = qt * 64 + w * 16 + quad * 4 + r;
        int orow = (b * T_SEQ + t) * 1024 + h * 64;
#pragma unroll
        for (int ds = 0; ds < 4; ++ds)
            AO[orow + ds * 16 + lane15] = f2bf(oacc[ds][r] * inv);
    }
}

// ---------------------------------------------------------------------------
extern "C" void kernel_launch(void* const* d_in, const int* in_sizes, int n_in,
                              void* d_out, int out_size, void* d_ws, size_t ws_size,
                              hipStream_t stream)
{
    const void* x   = d_in[0];
    const void* qWp = d_in[1];
    const void* qWi = d_in[2];
    const void* qWd = d_in[3];
    const void* qWg = d_in[4];
    const void* qbg = d_in[5];
    const void* kWp = d_in[6];
    const void* kWi = d_in[7];
    const void* kWd = d_in[8];
    const void* kWg = d_in[9];
    const void* kbg = d_in[10];
    const void* vWp = d_in[11];
    const void* vWi = d_in[12];
    const void* vWd = d_in[13];
    const void* vWg = d_in[14];
    const void* vbg = d_in[15];
    const void* oW  = d_in[16];
    const void* ob  = d_in[17];

    // ws layout (33 MiB total — unchanged, proven):
    int*   flag = (int*)d_ws;
    float* fws  = (float*)d_ws;
    float* csum = fws + 64;
    float* gq   = csum + 32768;
    float* gk   = gq + 3 * M_ROWS;
    float* gv   = gk + 3 * M_ROWS;
    const size_t SZ = (size_t)M_ROWS * D_MODEL;
    u16* Ib = (u16*)((char*)d_ws + (1u << 20));
    u16* AO = Ib;                  // alias, disjoint in time
    u16* Qh = Ib + SZ;
    u16* Kh = Qh + SZ;
    u16* Vh = Kh + SZ;

    detect_kernel<<<1, 64, 0, stream>>>((const u32*)x, flag);
    scan_partial<<<128, 256, 0, stream>>>(x, csum, flag);
    scan_final<<<128, 256, 0, stream>>>(x, csum, Ib, flag);
    gates_kernel<<<M_ROWS, 64, 0, stream>>>(x, qWg, qbg, kWg, kbg, vWg, vbg,
                                            gq, gk, gv, flag);

    GemmArgs pa;
    pa.W[0][0] = qWp; pa.W[0][1] = qWi; pa.W[0][2] = qWd;
    pa.W[1][0] = kWp; pa.W[1][1] = kWi; pa.W[1][2] = kWd;
    pa.W[2][0] = vWp; pa.W[2][1] = vWi; pa.W[2][2] = vWd;
    pa.G[0] = gq; pa.G[1] = gk; pa.G[2] = gv;
    pa.C[0] = Qh; pa.C[1] = Kh; pa.C[2] = Vh;
    mfma_gemm<0, 128><<<dim3(8, 32, 3), 256, 0, stream>>>(
        x, Ib, nullptr, pa, nullptr, nullptr, flag, 3072);

    attn_mfma<<<B_SZ * N_HEADS * (T_SEQ / 64), 256, 0, stream>>>(Qh, Kh, Vh, AO);

    GemmArgs oa = {};
    oa.W[0][0] = oW;
    mfma_gemm<1, 64><<<dim3(8, 64, 1), 256, 0, stream>>>(
        nullptr, nullptr, AO, oa, ob, d_out, flag, 1024);
}